// Round 20
// baseline (114.202 us; speedup 1.0000x reference)
//
#include <hip/hip_runtime.h>

// Forbid FMA contraction EVERYWHERE: distances must be bit-identical to
// numpy's unfused ((dx*dx + dy*dy) + dz*dz) in main loop AND fallback.
#pragma clang fp contract(off)

typedef unsigned long long u64;
typedef unsigned int u32;
typedef unsigned short u16;
typedef float f32x2 __attribute__((ext_vector_type(2)));

#define BB 8
#define LL 2048
#define MM 4096
#define KK 25
#define WPB 16           // waves per block
#define QPW 2            // queries per wave (shared LDS candidate stream)
#define TPB 1024
#define CAP 3072         // compacted-valid capacity (V ~ 2048 +- 32; P(V>CAP)~0)
#define SENT  0xFFFFFFFFFFFFFFFFull
#define SENTH 0xFFFFFFFFu   // exhausted marker for value words (> inf-bits+1)

// Wave64 min-reduce -> wave-uniform scalar (proven round-9 DPP ladder).
static __device__ __forceinline__ u32 wave_min_u32(u32 x) {
    u32 t;
    t = (u32)__builtin_amdgcn_update_dpp(0, (int)x, 0xB1, 0xF, 0xF, true);   // xor1
    x = t < x ? t : x;
    t = (u32)__builtin_amdgcn_update_dpp(0, (int)x, 0x4E, 0xF, 0xF, true);   // xor2
    x = t < x ? t : x;
    t = (u32)__builtin_amdgcn_update_dpp(0, (int)x, 0x141, 0xF, 0xF, true);  // half-row mirror
    x = t < x ? t : x;
    t = (u32)__builtin_amdgcn_update_dpp(0, (int)x, 0x140, 0xF, 0xF, true);  // row mirror
    x = t < x ? t : x;
    t = (u32)__builtin_amdgcn_update_dpp((int)x, (int)x, 0x142, 0xF, 0xF, false); // row_bcast15
    x = t < x ? t : x;
    t = (u32)__builtin_amdgcn_update_dpp((int)x, (int)x, 0x143, 0xF, 0xF, false); // row_bcast31
    x = t < x ? t : x;
    return (u32)__builtin_amdgcn_readlane((int)x, 63);
}

// ROUND 31 = r30 (42.2us, absmax 0) + QPW=2 (two queries share each wave's
// candidate stream). Ledger: staging+main 24.6 (LDS-pipe ~10-12us of it:
// 96 b64 x 512B per query, 403MB chip-total), selection 10.3, merge 7.3.
// QPW=2 halves main-loop LDS traffic AND staging total AND runs in ONE
// residency round (512 blocks = 2/CU). r12's regression causes are gone:
// extraction is now the flat selection (run twice, work-conserving, guarded
// by WAVE-UNIFORM live flags), not 2x serial ladders; dead slots skip
// selection+merge entirely (only mirrored main-loop distance wasted ~2%).
// Register watch: dual cascade + unroll-4 window ~54 VGPR (<64 cap);
// FETCH/WRITE is the spill falsifier.
__global__ void __launch_bounds__(TPB, 8) knn_kernel(
    const float* __restrict__ CB, const float* __restrict__ maskA,
    const float* __restrict__ Y, const int* __restrict__ Yt,
    const int* __restrict__ Ym, float* __restrict__ out)
{
    __shared__ __align__(16) float sX[CAP];   // 12 KiB each
    __shared__ __align__(16) float sY[CAP];
    __shared__ __align__(16) float sZ[CAP];
    __shared__ u16 sT16[CAP];                 // slot -> Yt value (6 KiB)
    __shared__ u16 sMidx[64];                 // first 64 masked indices (p order)
    __shared__ int sWinc[16];
    __shared__ int sWbase[16];
    __shared__ int sVtot;
    __shared__ u64 sExt[WPB][64];             // survivor scatter (8 KiB)
    __shared__ u64 sR[WPB][KK];               // rank->key (3.2 KiB)

    const int tid  = threadIdx.x;
    const int lane = tid & 63;
    const int wv   = tid >> 6;
    const int blk  = blockIdx.x;
    const int b    = blk >> 6;        // 64 blocks per batch (LL/(WPB*QPW))
    const int qg   = blk & 63;

    const float* Yb  = Y  + (size_t)b * MM * 3;
    const int*   Ymb = Ym + (size_t)b * MM;
    const int*   Ytb = Yt + (size_t)b * MM;

    // ---- staging: stable compaction of valid candidates (r16, proven) ----
    const int p0 = tid << 2;
    const float4 f0 = *(const float4*)(Yb + 3 * p0);
    const float4 f1 = *(const float4*)(Yb + 3 * p0 + 4);
    const float4 f2 = *(const float4*)(Yb + 3 * p0 + 8);
    const int4   m4 = *(const int4*)(Ymb + p0);
    const int4   t4 = *(const int4*)(Ytb + p0);
    const int v0 = (m4.x != 0), v1 = (m4.y != 0), v2 = (m4.z != 0), v3 = (m4.w != 0);
    const int cnt0 = v0 + v1 + v2 + v3;

    int inc = cnt0;
#pragma unroll
    for (int off = 1; off < 64; off <<= 1) {
        const int t = __shfl_up(inc, off, 64);
        if (lane >= off) inc += t;
    }
    if (lane == 63) sWinc[wv] = inc;
    __syncthreads();
    if (tid < 16) {
        const int x = sWinc[tid];
        int ix = x;
#pragma unroll
        for (int off = 1; off < 16; off <<= 1) {
            const int t = __shfl_up(ix, off, 16);
            if (tid >= off) ix += t;
        }
        sWbase[tid] = ix - x;
        if (tid == 15) sVtot = ix;
    }
    __syncthreads();

    {
        int bs = sWbase[wv] + inc - cnt0;
        int mb = p0 - bs;
        if (v0) { sX[bs]=f0.x; sY[bs]=f0.y; sZ[bs]=f0.z; sT16[bs]=(u16)t4.x; bs++; }
        else    { if (mb < 64) sMidx[mb] = (u16)(p0 + 0); mb++; }
        if (v1) { sX[bs]=f0.w; sY[bs]=f1.x; sZ[bs]=f1.y; sT16[bs]=(u16)t4.y; bs++; }
        else    { if (mb < 64) sMidx[mb] = (u16)(p0 + 1); mb++; }
        if (v2) { sX[bs]=f1.z; sY[bs]=f1.w; sZ[bs]=f2.x; sT16[bs]=(u16)t4.z; bs++; }
        else    { if (mb < 64) sMidx[mb] = (u16)(p0 + 2); mb++; }
        if (v3) { sX[bs]=f2.y; sY[bs]=f2.z; sZ[bs]=f2.w; sT16[bs]=(u16)t4.w; bs++; }
        else    { if (mb < 64) sMidx[mb] = (u16)(p0 + 3); mb++; }
    }
    const int V  = sVtot;
    const int NJ = (V + 127) >> 7;            // 128-slot blocks (~16)
    for (int c = V + tid; c < (NJ << 7); c += TPB) {
        sX[c] = __builtin_inff(); sY[c] = 0.0f; sZ[c] = 0.0f; sT16[c] = 0;
    }
    __syncthreads();

    const int lA = qg * (WPB * QPW) + (wv << 1);
    const int qA = b * LL + lA;
    const int qB = qA + 1;

    float* out_y = out;
    float* out_t = out + (size_t)BB * LL * KK * 3;
    float* out_m = out_t + (size_t)BB * LL * KK;
    float* out_d = out_m + (size_t)BB * LL * KK;

    // ---- fast path: masked query (verified r2..r30) ----
    auto fastout = [&](int q) {
        if (lane < KK) {
            const int p = lane;
            const size_t o = (size_t)q * KK + lane;
            out_y[3 * o + 0] = Yb[3 * p + 0];
            out_y[3 * o + 1] = Yb[3 * p + 1];
            out_y[3 * o + 2] = Yb[3 * p + 2];
            out_t[o] = (float)Ytb[p];
            out_m[o] = (float)Ymb[p];
            if (lane == 0) out_d[q] = sqrtf(1000.0f);
        }
    };

    const bool liveA = maskA[qA] != 0.0f;   // wave-uniform
    const bool liveB = maskA[qB] != 0.0f;
    if (!liveA) fastout(qA);
    if (!liveB) fastout(qB);
    if (!liveA && !liveB) return;

    float cAx = CB[3 * qA + 0], cAy = CB[3 * qA + 1], cAz = CB[3 * qA + 2];
    float cBx = CB[3 * qB + 0], cBy = CB[3 * qB + 1], cBz = CB[3 * qB + 2];
    // mirror live coords into the dead slot (dead slot never reaches
    // selection/merge; this only keeps the main loop branch-free)
    if (!liveA) { cAx = cBx; cAy = cBy; cAz = cBz; }
    if (!liveB) { cBx = cAx; cBy = cAy; cBz = cAz; }

    // ---- fused packed distance + dual per-lane stable top-4 cascades ----
    float vA1 = 3.0e38f, vA2 = 3.0e38f, vA3 = 3.0e38f, vA4 = 3.0e38f;
    float vB1 = 3.0e38f, vB2 = 3.0e38f, vB3 = 3.0e38f, vB4 = 3.0e38f;
    u32 JA = 0u, JB = 0u;           // byte-packed ids id=(j<<1)|half
    const u32 SEL1 = 0x06050400u;
    const u32 SEL2 = 0x06050004u;
    const u32 SEL3 = 0x06000504u;
    const u32 SEL4 = 0x00060504u;
    auto ins = [&](float v, u32 id, float& w1, float& w2, float& w3, float& w4,
                   u32& JJ) {
        const bool c1 = v < w1, c2 = v < w2, c3 = v < w3, c4 = v < w4;
        const u32 sel = c1 ? SEL1 : (c2 ? SEL2 : (c3 ? SEL3 : SEL4));
        const u32 Jp  = __builtin_amdgcn_perm(JJ, id, sel);
        const float n2 = __builtin_amdgcn_fmed3f(v, w1, w2);
        const float n3 = __builtin_amdgcn_fmed3f(v, w2, w3);
        const float n4 = __builtin_amdgcn_fmed3f(v, w3, w4);
        w1 = fminf(v, w1);
        w2 = n2; w3 = n3; w4 = n4;
        JJ = c4 ? Jp : JJ;
    };

    const f32x2 cAxx = {cAx, cAx}, cAyy = {cAy, cAy}, cAzz = {cAz, cAz};
    const f32x2 cBxx = {cBx, cBx}, cByy = {cBy, cBy}, cBzz = {cBz, cBz};
#pragma unroll 4
    for (int j = 0; j < NJ; ++j) {
        const int base = (j << 7) + (lane << 1);
        const f32x2 xp = *(const f32x2*)&sX[base];
        const f32x2 yp = *(const f32x2*)&sY[base];
        const f32x2 zp = *(const f32x2*)&sZ[base];
        const f32x2 dxA = cAxx - xp;
        const f32x2 dyA = cAyy - yp;
        const f32x2 dzA = cAzz - zp;
        const f32x2 dA = (dxA * dxA + dyA * dyA) + dzA * dzA;
        const f32x2 dxB = cBxx - xp;
        const f32x2 dyB = cByy - yp;
        const f32x2 dzB = cBzz - zp;
        const f32x2 dB = (dxB * dxB + dyB * dyB) + dzB * dzB;
        ins(dA.x, (u32)(j << 1),       vA1, vA2, vA3, vA4, JA);
        ins(dA.y, (u32)((j << 1) | 1), vA1, vA2, vA3, vA4, JA);
        ins(dB.x, (u32)(j << 1),       vB1, vB2, vB3, vB4, JB);
        ins(dB.y, (u32)((j << 1) | 1), vB1, vB2, vB3, vB4, JB);
    }

    auto slotof = [&](u32 id) -> u32 {
        return ((id >> 1) << 7) | (u32)(lane << 1) | (id & 1u);
    };

    // ---- per-query: flat selection -> (rare) resumed ladder -> merge ----
    // r26/r30 logic verbatim, parameterized. sExt[wv]/sR[wv] reused
    // sequentially (same wave; LDS ops ordered by lgkmcnt).
    auto process = [&](float v1f, float v2f, float v3f, float v4f, u32 J,
                       float cx, float cy, float cz, int q) {
        const u32 s1 = slotof( J        & 0xFFu);
        const u32 s2 = slotof((J >>  8) & 0xFFu);
        const u32 s3 = slotof((J >> 16) & 0xFFu);
        const u32 s4 = slotof((J >> 24) & 0xFFu);
        u32 h1 = __float_as_uint(v1f) + 1u;
        u32 h2 = __float_as_uint(v2f) + 1u;
        u32 h3 = __float_as_uint(v3f) + 1u;
        u32 h4 = __float_as_uint(v4f) + 1u;
        u64 lref = ((u64)h4 << 32) | s4;   // refill anchor (updated on refill)

        bool ladder = false;
        int  rstart = 0;
        {
            const u32 T = wave_min_u32(h4);
            const bool c1 = (h1 <= T), c2 = (h2 <= T), c3 = (h3 <= T), c4 = (h4 <= T);
            const u64 b1 = __ballot(c1), b2 = __ballot(c2);
            const u64 b3 = __ballot(c3), b4 = __ballot(c4);
            const int n1 = __popcll(b1), n2 = __popcll(b2), n3 = __popcll(b3);
            const int total = n1 + n2 + n3 + __popcll(b4);
            if (total > 64) {
                ladder = true;            // P~0: full ladder, chain unshifted
            } else {
                const u64 below = (1ull << lane) - 1ull;
                u64* sE = sExt[wv];
                sE[lane] = SENT;          // pad [total,64)
                if (lane == 24) sR[wv][24] = SENT;   // incomplete-detector
                int pos = __popcll(b1 & below);
                if (c1) sE[pos] = ((u64)h1 << 32) | s1;
                pos = n1 + __popcll(b2 & below);
                if (c2) sE[pos] = ((u64)h2 << 32) | s2;
                pos = n1 + n2 + __popcll(b3 & below);
                if (c3) sE[pos] = ((u64)h3 << 32) | s3;
                pos = n1 + n2 + n3 + __popcll(b4 & below);
                if (c4) sE[pos] = ((u64)h4 << 32) | s4;
                const u64 mk = sE[lane];
                int rank = 0;
                const int tot = (total + 7) & ~7;
#pragma unroll 8
                for (int i = 0; i < tot; ++i)
                    rank += (sE[i] < mk) ? 1 : 0;
                if (rank < KK && mk != SENT) sR[wv][rank] = mk;
                const u64 K25 = sR[wv][24];
                if (__any(lref < K25)) {
                    // ranks with value < T strictly are unconditionally
                    // correct (hidden keys all have value >= T).
                    const int scnt = (h1 < T) + (h2 < T) + (h3 < T) + (h4 < T);
                    rstart = __popcll(__ballot(h1 < T)) + __popcll(__ballot(h2 < T))
                           + __popcll(__ballot(h3 < T)) + __popcll(__ballot(h4 < T));
#pragma unroll
                    for (int k = 0; k < 4; ++k)
                        if (k < scnt) { h1 = h2; h2 = h3; h3 = h4; h4 = SENTH; J >>= 8; }
                    ladder = true;        // fire => rstart <= 24 (proven)
                }
            }
        }

        if (ladder) {
#pragma unroll 1
            for (int it = rstart; it < KK; ++it) {
                if (__any(h1 == SENTH)) {
                    const bool need = (h1 == SENTH);
                    u64 found = SENT;
                    const int NI = NJ << 1;
#pragma unroll 4
                    for (int id = 0; id < NI; ++id) {
                        const u32 s = slotof((u32)id);
                        const float dx = cx - sX[s];
                        const float dy = cy - sY[s];
                        const float dz = cz - sZ[s];
                        const float v = (dx * dx + dy * dy) + dz * dz;
                        const u64 key = ((u64)(__float_as_uint(v) + 1u) << 32) | s;
                        if (key > lref && key < found) found = key;
                    }
                    if (need) {
                        const u32 s = (u32)found & 0xFFFFu;
                        h1 = (u32)(found >> 32);
                        J = (J & ~0xFFu) | (((s >> 7) << 1) | (s & 1u));
                        lref = found;
                    }
                }
                const u32 bv = wave_min_u32(h1);
                const u64 ball = __ballot(h1 == bv);
                bool win = (h1 == bv);
                if (__popcll(ball) != 1) {    // exact value tie: min slot wins
                    const u32 vl = slotof(J & 0xFFu);
                    u32 cp = win ? vl : 0xFFFFFFFFu;
#pragma unroll
                    for (int off = 32; off; off >>= 1) {
                        const u32 o = __shfl_xor(cp, off, 64);
                        cp = (o < cp) ? o : cp;
                    }
                    win = win && (vl == cp);
                }
                if (win) {                    // unique keys -> exactly one lane
                    sR[wv][it] = ((u64)h1 << 32) | slotof(J & 0xFFu);
                    h1 = h2; h2 = h3; h3 = h4; h4 = SENTH;
                    J >>= 8;
                }
            }
        }

        // merge valid winners with the constant masked run, then output
        u64 myk = 0;
        if (lane < KK) myk = sR[wv][lane];
        const u32 mvh   = (u32)(myk >> 32);
        const u32 mslot = (u32)myk & 0xFFFFu;
        const bool less = (lane < KK) && (mvh < 0x447A0001u);  // v < 1000.0f
        const int nless = __popcll(__ballot(less));
        if (lane < KK) {
            const size_t o = (size_t)q * KK + lane;
            if (lane < nless) {
                out_y[3 * o + 0] = sX[mslot];
                out_y[3 * o + 1] = sY[mslot];
                out_y[3 * o + 2] = sZ[mslot];
                out_t[o] = (float)sT16[mslot];
                out_m[o] = 1.0f;
                if (lane == 0) out_d[q] = sqrtf(__uint_as_float(mvh - 1u));
            } else {
                const int p = (int)sMidx[lane - nless];
                out_y[3 * o + 0] = Yb[3 * p + 0];
                out_y[3 * o + 1] = Yb[3 * p + 1];
                out_y[3 * o + 2] = Yb[3 * p + 2];
                out_t[o] = (float)Ytb[p];
                out_m[o] = 0.0f;
                if (lane == 0) out_d[q] = sqrtf(1000.0f);   // nless==0 outlier
            }
        }
    };

    if (liveA) process(vA1, vA2, vA3, vA4, JA, cAx, cAy, cAz, qA);
    if (liveB) process(vB1, vB2, vB3, vB4, JB, cBx, cBy, cBz, qB);
}

extern "C" void kernel_launch(void* const* d_in, const int* in_sizes, int n_in,
                              void* d_out, int out_size, void* d_ws, size_t ws_size,
                              hipStream_t stream) {
    const float* CB   = (const float*)d_in[0];
    const float* mask = (const float*)d_in[1];
    const float* Y    = (const float*)d_in[2];
    const int*   Yt   = (const int*)d_in[3];
    const int*   Ym   = (const int*)d_in[4];
    float* out = (float*)d_out;

    dim3 grid(BB * LL / (WPB * QPW));   // 512 blocks = one full residency round
    dim3 block(TPB);
    hipLaunchKernelGGL(knn_kernel, grid, block, 0, stream, CB, mask, Y, Yt, Ym, out);
}

// Round 21
// 102.518 us; speedup vs baseline: 1.1140x; 1.1140x over previous
//
#include <hip/hip_runtime.h>

// Forbid FMA contraction EVERYWHERE: distances must be bit-identical to
// numpy's unfused ((dx*dx + dy*dy) + dz*dz) in main loop AND fallback.
#pragma clang fp contract(off)

typedef unsigned long long u64;
typedef unsigned int u32;
typedef unsigned short u16;
typedef float f32x2 __attribute__((ext_vector_type(2)));

#define BB 8
#define LL 2048
#define MM 4096
#define KK 25
#define WPB 16           // waves per block
#define QPW 2            // queries per wave (shared LDS candidate stream)
#define TPB 1024
#define CAP 3072         // compacted-valid capacity (V ~ 2048 +- 32; P(V>CAP)~0)
#define SENT  0xFFFFFFFFFFFFFFFFull
#define SENTH 0xFFFFFFFFu   // exhausted marker for value words (> inf-bits+1)

// Wave64 min-reduce -> wave-uniform scalar (proven round-9 DPP ladder).
static __device__ __forceinline__ u32 wave_min_u32(u32 x) {
    u32 t;
    t = (u32)__builtin_amdgcn_update_dpp(0, (int)x, 0xB1, 0xF, 0xF, true);   // xor1
    x = t < x ? t : x;
    t = (u32)__builtin_amdgcn_update_dpp(0, (int)x, 0x4E, 0xF, 0xF, true);   // xor2
    x = t < x ? t : x;
    t = (u32)__builtin_amdgcn_update_dpp(0, (int)x, 0x141, 0xF, 0xF, true);  // half-row mirror
    x = t < x ? t : x;
    t = (u32)__builtin_amdgcn_update_dpp(0, (int)x, 0x140, 0xF, 0xF, true);  // row mirror
    x = t < x ? t : x;
    t = (u32)__builtin_amdgcn_update_dpp((int)x, (int)x, 0x142, 0xF, 0xF, false); // row_bcast15
    x = t < x ? t : x;
    t = (u32)__builtin_amdgcn_update_dpp((int)x, (int)x, 0x143, 0xF, 0xF, false); // row_bcast31
    x = t < x ? t : x;
    return (u32)__builtin_amdgcn_readlane((int)x, 63);
}

// ROUND 32 = r31 (QPW=2; regressed on SPILL: WRITE 8->70.7MB, FETCH
// 2.8->17.9MB — the pre-registered falsifier) with the main-loop prefetch
// window halved: unroll 4 -> 2. Live set drops ~46 -> ~34 VGPR (12 in-
// flight b64 regs instead of 24), under the launch_bounds(1024,8) 64-cap.
// r18's "unroll 2 stalls" lesson does NOT transfer: with 2 queries per
// candidate the compute-per-load DOUBLED (~30 VALU/iter vs 15), so the
// 2-iter window covers what the 4-iter window covered at QPW=1.
// All else verbatim r31 (passed, absmax 0). Decisive counters: FETCH ~2.8,
// WRITE ~8.06 => spill gone; then dur should land ~34-38.
__global__ void __launch_bounds__(TPB, 8) knn_kernel(
    const float* __restrict__ CB, const float* __restrict__ maskA,
    const float* __restrict__ Y, const int* __restrict__ Yt,
    const int* __restrict__ Ym, float* __restrict__ out)
{
    __shared__ __align__(16) float sX[CAP];   // 12 KiB each
    __shared__ __align__(16) float sY[CAP];
    __shared__ __align__(16) float sZ[CAP];
    __shared__ u16 sT16[CAP];                 // slot -> Yt value (6 KiB)
    __shared__ u16 sMidx[64];                 // first 64 masked indices (p order)
    __shared__ int sWinc[16];
    __shared__ int sWbase[16];
    __shared__ int sVtot;
    __shared__ u64 sExt[WPB][64];             // survivor scatter (8 KiB)
    __shared__ u64 sR[WPB][KK];               // rank->key (3.2 KiB)

    const int tid  = threadIdx.x;
    const int lane = tid & 63;
    const int wv   = tid >> 6;
    const int blk  = blockIdx.x;
    const int b    = blk >> 6;        // 64 blocks per batch (LL/(WPB*QPW))
    const int qg   = blk & 63;

    const float* Yb  = Y  + (size_t)b * MM * 3;
    const int*   Ymb = Ym + (size_t)b * MM;
    const int*   Ytb = Yt + (size_t)b * MM;

    // ---- staging: stable compaction of valid candidates (r16, proven) ----
    const int p0 = tid << 2;
    const float4 f0 = *(const float4*)(Yb + 3 * p0);
    const float4 f1 = *(const float4*)(Yb + 3 * p0 + 4);
    const float4 f2 = *(const float4*)(Yb + 3 * p0 + 8);
    const int4   m4 = *(const int4*)(Ymb + p0);
    const int4   t4 = *(const int4*)(Ytb + p0);
    const int v0 = (m4.x != 0), v1 = (m4.y != 0), v2 = (m4.z != 0), v3 = (m4.w != 0);
    const int cnt0 = v0 + v1 + v2 + v3;

    int inc = cnt0;
#pragma unroll
    for (int off = 1; off < 64; off <<= 1) {
        const int t = __shfl_up(inc, off, 64);
        if (lane >= off) inc += t;
    }
    if (lane == 63) sWinc[wv] = inc;
    __syncthreads();
    if (tid < 16) {
        const int x = sWinc[tid];
        int ix = x;
#pragma unroll
        for (int off = 1; off < 16; off <<= 1) {
            const int t = __shfl_up(ix, off, 16);
            if (tid >= off) ix += t;
        }
        sWbase[tid] = ix - x;
        if (tid == 15) sVtot = ix;
    }
    __syncthreads();

    {
        int bs = sWbase[wv] + inc - cnt0;
        int mb = p0 - bs;
        if (v0) { sX[bs]=f0.x; sY[bs]=f0.y; sZ[bs]=f0.z; sT16[bs]=(u16)t4.x; bs++; }
        else    { if (mb < 64) sMidx[mb] = (u16)(p0 + 0); mb++; }
        if (v1) { sX[bs]=f0.w; sY[bs]=f1.x; sZ[bs]=f1.y; sT16[bs]=(u16)t4.y; bs++; }
        else    { if (mb < 64) sMidx[mb] = (u16)(p0 + 1); mb++; }
        if (v2) { sX[bs]=f1.z; sY[bs]=f1.w; sZ[bs]=f2.x; sT16[bs]=(u16)t4.z; bs++; }
        else    { if (mb < 64) sMidx[mb] = (u16)(p0 + 2); mb++; }
        if (v3) { sX[bs]=f2.y; sY[bs]=f2.z; sZ[bs]=f2.w; sT16[bs]=(u16)t4.w; bs++; }
        else    { if (mb < 64) sMidx[mb] = (u16)(p0 + 3); mb++; }
    }
    const int V  = sVtot;
    const int NJ = (V + 127) >> 7;            // 128-slot blocks (~16)
    for (int c = V + tid; c < (NJ << 7); c += TPB) {
        sX[c] = __builtin_inff(); sY[c] = 0.0f; sZ[c] = 0.0f; sT16[c] = 0;
    }
    __syncthreads();

    const int lA = qg * (WPB * QPW) + (wv << 1);
    const int qA = b * LL + lA;
    const int qB = qA + 1;

    float* out_y = out;
    float* out_t = out + (size_t)BB * LL * KK * 3;
    float* out_m = out_t + (size_t)BB * LL * KK;
    float* out_d = out_m + (size_t)BB * LL * KK;

    // ---- fast path: masked query (verified r2..r31) ----
    auto fastout = [&](int q) {
        if (lane < KK) {
            const int p = lane;
            const size_t o = (size_t)q * KK + lane;
            out_y[3 * o + 0] = Yb[3 * p + 0];
            out_y[3 * o + 1] = Yb[3 * p + 1];
            out_y[3 * o + 2] = Yb[3 * p + 2];
            out_t[o] = (float)Ytb[p];
            out_m[o] = (float)Ymb[p];
            if (lane == 0) out_d[q] = sqrtf(1000.0f);
        }
    };

    const bool liveA = maskA[qA] != 0.0f;   // wave-uniform
    const bool liveB = maskA[qB] != 0.0f;
    if (!liveA) fastout(qA);
    if (!liveB) fastout(qB);
    if (!liveA && !liveB) return;

    float cAx = CB[3 * qA + 0], cAy = CB[3 * qA + 1], cAz = CB[3 * qA + 2];
    float cBx = CB[3 * qB + 0], cBy = CB[3 * qB + 1], cBz = CB[3 * qB + 2];
    // mirror live coords into the dead slot (dead slot never reaches
    // selection/merge; this only keeps the main loop branch-free)
    if (!liveA) { cAx = cBx; cAy = cBy; cAz = cBz; }
    if (!liveB) { cBx = cAx; cBy = cAy; cBz = cAz; }

    // ---- fused packed distance + dual per-lane stable top-4 cascades ----
    float vA1 = 3.0e38f, vA2 = 3.0e38f, vA3 = 3.0e38f, vA4 = 3.0e38f;
    float vB1 = 3.0e38f, vB2 = 3.0e38f, vB3 = 3.0e38f, vB4 = 3.0e38f;
    u32 JA = 0u, JB = 0u;           // byte-packed ids id=(j<<1)|half
    const u32 SEL1 = 0x06050400u;
    const u32 SEL2 = 0x06050004u;
    const u32 SEL3 = 0x06000504u;
    const u32 SEL4 = 0x00060504u;
    auto ins = [&](float v, u32 id, float& w1, float& w2, float& w3, float& w4,
                   u32& JJ) {
        const bool c1 = v < w1, c2 = v < w2, c3 = v < w3, c4 = v < w4;
        const u32 sel = c1 ? SEL1 : (c2 ? SEL2 : (c3 ? SEL3 : SEL4));
        const u32 Jp  = __builtin_amdgcn_perm(JJ, id, sel);
        const float n2 = __builtin_amdgcn_fmed3f(v, w1, w2);
        const float n3 = __builtin_amdgcn_fmed3f(v, w2, w3);
        const float n4 = __builtin_amdgcn_fmed3f(v, w3, w4);
        w1 = fminf(v, w1);
        w2 = n2; w3 = n3; w4 = n4;
        JJ = c4 ? Jp : JJ;
    };

    const f32x2 cAxx = {cAx, cAx}, cAyy = {cAy, cAy}, cAzz = {cAz, cAz};
    const f32x2 cBxx = {cBx, cBx}, cByy = {cBy, cBy}, cBzz = {cBz, cBz};
#pragma unroll 2
    for (int j = 0; j < NJ; ++j) {
        const int base = (j << 7) + (lane << 1);
        const f32x2 xp = *(const f32x2*)&sX[base];
        const f32x2 yp = *(const f32x2*)&sY[base];
        const f32x2 zp = *(const f32x2*)&sZ[base];
        const f32x2 dxA = cAxx - xp;
        const f32x2 dyA = cAyy - yp;
        const f32x2 dzA = cAzz - zp;
        const f32x2 dA = (dxA * dxA + dyA * dyA) + dzA * dzA;
        const f32x2 dxB = cBxx - xp;
        const f32x2 dyB = cByy - yp;
        const f32x2 dzB = cBzz - zp;
        const f32x2 dB = (dxB * dxB + dyB * dyB) + dzB * dzB;
        ins(dA.x, (u32)(j << 1),       vA1, vA2, vA3, vA4, JA);
        ins(dA.y, (u32)((j << 1) | 1), vA1, vA2, vA3, vA4, JA);
        ins(dB.x, (u32)(j << 1),       vB1, vB2, vB3, vB4, JB);
        ins(dB.y, (u32)((j << 1) | 1), vB1, vB2, vB3, vB4, JB);
    }

    auto slotof = [&](u32 id) -> u32 {
        return ((id >> 1) << 7) | (u32)(lane << 1) | (id & 1u);
    };

    // ---- per-query: flat selection -> (rare) resumed ladder -> merge ----
    // r26/r30 logic verbatim, parameterized. sExt[wv]/sR[wv] reused
    // sequentially (same wave; LDS ops ordered by lgkmcnt).
    auto process = [&](float v1f, float v2f, float v3f, float v4f, u32 J,
                       float cx, float cy, float cz, int q) {
        const u32 s1 = slotof( J        & 0xFFu);
        const u32 s2 = slotof((J >>  8) & 0xFFu);
        const u32 s3 = slotof((J >> 16) & 0xFFu);
        const u32 s4 = slotof((J >> 24) & 0xFFu);
        u32 h1 = __float_as_uint(v1f) + 1u;
        u32 h2 = __float_as_uint(v2f) + 1u;
        u32 h3 = __float_as_uint(v3f) + 1u;
        u32 h4 = __float_as_uint(v4f) + 1u;
        u64 lref = ((u64)h4 << 32) | s4;   // refill anchor (updated on refill)

        bool ladder = false;
        int  rstart = 0;
        {
            const u32 T = wave_min_u32(h4);
            const bool c1 = (h1 <= T), c2 = (h2 <= T), c3 = (h3 <= T), c4 = (h4 <= T);
            const u64 b1 = __ballot(c1), b2 = __ballot(c2);
            const u64 b3 = __ballot(c3), b4 = __ballot(c4);
            const int n1 = __popcll(b1), n2 = __popcll(b2), n3 = __popcll(b3);
            const int total = n1 + n2 + n3 + __popcll(b4);
            if (total > 64) {
                ladder = true;            // P~0: full ladder, chain unshifted
            } else {
                const u64 below = (1ull << lane) - 1ull;
                u64* sE = sExt[wv];
                sE[lane] = SENT;          // pad [total,64)
                if (lane == 24) sR[wv][24] = SENT;   // incomplete-detector
                int pos = __popcll(b1 & below);
                if (c1) sE[pos] = ((u64)h1 << 32) | s1;
                pos = n1 + __popcll(b2 & below);
                if (c2) sE[pos] = ((u64)h2 << 32) | s2;
                pos = n1 + n2 + __popcll(b3 & below);
                if (c3) sE[pos] = ((u64)h3 << 32) | s3;
                pos = n1 + n2 + n3 + __popcll(b4 & below);
                if (c4) sE[pos] = ((u64)h4 << 32) | s4;
                const u64 mk = sE[lane];
                int rank = 0;
                const int tot = (total + 7) & ~7;
#pragma unroll 8
                for (int i = 0; i < tot; ++i)
                    rank += (sE[i] < mk) ? 1 : 0;
                if (rank < KK && mk != SENT) sR[wv][rank] = mk;
                const u64 K25 = sR[wv][24];
                if (__any(lref < K25)) {
                    // ranks with value < T strictly are unconditionally
                    // correct (hidden keys all have value >= T).
                    const int scnt = (h1 < T) + (h2 < T) + (h3 < T) + (h4 < T);
                    rstart = __popcll(__ballot(h1 < T)) + __popcll(__ballot(h2 < T))
                           + __popcll(__ballot(h3 < T)) + __popcll(__ballot(h4 < T));
#pragma unroll
                    for (int k = 0; k < 4; ++k)
                        if (k < scnt) { h1 = h2; h2 = h3; h3 = h4; h4 = SENTH; J >>= 8; }
                    ladder = true;        // fire => rstart <= 24 (proven)
                }
            }
        }

        if (ladder) {
#pragma unroll 1
            for (int it = rstart; it < KK; ++it) {
                if (__any(h1 == SENTH)) {
                    const bool need = (h1 == SENTH);
                    u64 found = SENT;
                    const int NI = NJ << 1;
#pragma unroll 4
                    for (int id = 0; id < NI; ++id) {
                        const u32 s = slotof((u32)id);
                        const float dx = cx - sX[s];
                        const float dy = cy - sY[s];
                        const float dz = cz - sZ[s];
                        const float v = (dx * dx + dy * dy) + dz * dz;
                        const u64 key = ((u64)(__float_as_uint(v) + 1u) << 32) | s;
                        if (key > lref && key < found) found = key;
                    }
                    if (need) {
                        const u32 s = (u32)found & 0xFFFFu;
                        h1 = (u32)(found >> 32);
                        J = (J & ~0xFFu) | (((s >> 7) << 1) | (s & 1u));
                        lref = found;
                    }
                }
                const u32 bv = wave_min_u32(h1);
                const u64 ball = __ballot(h1 == bv);
                bool win = (h1 == bv);
                if (__popcll(ball) != 1) {    // exact value tie: min slot wins
                    const u32 vl = slotof(J & 0xFFu);
                    u32 cp = win ? vl : 0xFFFFFFFFu;
#pragma unroll
                    for (int off = 32; off; off >>= 1) {
                        const u32 o = __shfl_xor(cp, off, 64);
                        cp = (o < cp) ? o : cp;
                    }
                    win = win && (vl == cp);
                }
                if (win) {                    // unique keys -> exactly one lane
                    sR[wv][it] = ((u64)h1 << 32) | slotof(J & 0xFFu);
                    h1 = h2; h2 = h3; h3 = h4; h4 = SENTH;
                    J >>= 8;
                }
            }
        }

        // merge valid winners with the constant masked run, then output
        u64 myk = 0;
        if (lane < KK) myk = sR[wv][lane];
        const u32 mvh   = (u32)(myk >> 32);
        const u32 mslot = (u32)myk & 0xFFFFu;
        const bool less = (lane < KK) && (mvh < 0x447A0001u);  // v < 1000.0f
        const int nless = __popcll(__ballot(less));
        if (lane < KK) {
            const size_t o = (size_t)q * KK + lane;
            if (lane < nless) {
                out_y[3 * o + 0] = sX[mslot];
                out_y[3 * o + 1] = sY[mslot];
                out_y[3 * o + 2] = sZ[mslot];
                out_t[o] = (float)sT16[mslot];
                out_m[o] = 1.0f;
                if (lane == 0) out_d[q] = sqrtf(__uint_as_float(mvh - 1u));
            } else {
                const int p = (int)sMidx[lane - nless];
                out_y[3 * o + 0] = Yb[3 * p + 0];
                out_y[3 * o + 1] = Yb[3 * p + 1];
                out_y[3 * o + 2] = Yb[3 * p + 2];
                out_t[o] = (float)Ytb[p];
                out_m[o] = 0.0f;
                if (lane == 0) out_d[q] = sqrtf(1000.0f);   // nless==0 outlier
            }
        }
    };

    if (liveA) process(vA1, vA2, vA3, vA4, JA, cAx, cAy, cAz, qA);
    if (liveB) process(vB1, vB2, vB3, vB4, JB, cBx, cBy, cBz, qB);
}

extern "C" void kernel_launch(void* const* d_in, const int* in_sizes, int n_in,
                              void* d_out, int out_size, void* d_ws, size_t ws_size,
                              hipStream_t stream) {
    const float* CB   = (const float*)d_in[0];
    const float* mask = (const float*)d_in[1];
    const float* Y    = (const float*)d_in[2];
    const int*   Yt   = (const int*)d_in[3];
    const int*   Ym   = (const int*)d_in[4];
    float* out = (float*)d_out;

    dim3 grid(BB * LL / (WPB * QPW));   // 512 blocks = one full residency round
    dim3 block(TPB);
    hipLaunchKernelGGL(knn_kernel, grid, block, 0, stream, CB, mask, Y, Yt, Ym, out);
}

// Round 22
// 100.189 us; speedup vs baseline: 1.1399x; 1.0232x over previous
//
#include <hip/hip_runtime.h>

// Forbid FMA contraction EVERYWHERE: distances must be bit-identical to
// numpy's unfused ((dx*dx + dy*dy) + dz*dz) in main loop AND fallback.
#pragma clang fp contract(off)

typedef unsigned long long u64;
typedef unsigned int u32;
typedef unsigned short u16;
typedef float f32x2 __attribute__((ext_vector_type(2)));
typedef u64 u64x2 __attribute__((ext_vector_type(2)));

#define BB 8
#define LL 2048
#define MM 4096
#define KK 25
#define WPB 16           // waves (queries) per block
#define TPB 1024
#define CAP 3072         // compacted-valid capacity (V ~ 2048 +- 32; P(V>CAP)~0)
#define SENT  0xFFFFFFFFFFFFFFFFull
#define SENTH 0xFFFFFFFFu   // exhausted marker for value words (> inf-bits+1)

// Wave64 min-reduce -> wave-uniform scalar (proven round-9 DPP ladder).
static __device__ __forceinline__ u32 wave_min_u32(u32 x) {
    u32 t;
    t = (u32)__builtin_amdgcn_update_dpp(0, (int)x, 0xB1, 0xF, 0xF, true);   // xor1
    x = t < x ? t : x;
    t = (u32)__builtin_amdgcn_update_dpp(0, (int)x, 0x4E, 0xF, 0xF, true);   // xor2
    x = t < x ? t : x;
    t = (u32)__builtin_amdgcn_update_dpp(0, (int)x, 0x141, 0xF, 0xF, true);  // half-row mirror
    x = t < x ? t : x;
    t = (u32)__builtin_amdgcn_update_dpp(0, (int)x, 0x140, 0xF, 0xF, true);  // row mirror
    x = t < x ? t : x;
    t = (u32)__builtin_amdgcn_update_dpp((int)x, (int)x, 0x142, 0xF, 0xF, false); // row_bcast15
    x = t < x ? t : x;
    t = (u32)__builtin_amdgcn_update_dpp((int)x, (int)x, 0x143, 0xF, 0xF, false); // row_bcast31
    x = t < x ? t : x;
    return (u32)__builtin_amdgcn_readlane((int)x, 63);
}

// ROUND 33 = r30 (42.2us, absmax 0; the verified best: QPW=1, unroll-4 b64
// main, flat selection + resumed ladder, LDS-served epilogue) + ONE change:
// the selection rank loop reads survivor keys TWO per aligned ds_read_b128
// (sExt 16B-aligned; tot is a multiple of 8 so the i+=2 pair loop is exact;
// SENT pads compare correctly). ~56 b64 broadcasts -> ~28 b128 (8cyc for 2
// keys vs 2x6) = ~35% less LDS-pipe occupancy in the 10.3us selection.
// r32 post-mortem: QPW=2 clean (no spill) = 43.4 vs 42.2 — main loop is
// pipe-BALANCED (VALU<->LDS zero-sum), QPW structurally dead, reverted.
__global__ void __launch_bounds__(TPB, 8) knn_kernel(
    const float* __restrict__ CB, const float* __restrict__ maskA,
    const float* __restrict__ Y, const int* __restrict__ Yt,
    const int* __restrict__ Ym, float* __restrict__ out)
{
    __shared__ __align__(16) float sX[CAP];   // 12 KiB each
    __shared__ __align__(16) float sY[CAP];
    __shared__ __align__(16) float sZ[CAP];
    __shared__ u16 sT16[CAP];                 // slot -> Yt value (6 KiB)
    __shared__ u16 sMidx[64];                 // first 64 masked indices (p order)
    __shared__ int sWinc[16];
    __shared__ int sWbase[16];
    __shared__ int sVtot;
    __shared__ __align__(16) u64 sExt[WPB][64];   // survivor scatter (8 KiB)
    __shared__ u64 sR[WPB][KK];               // rank->key (3.2 KiB)

    const int tid  = threadIdx.x;
    const int lane = tid & 63;
    const int wv   = tid >> 6;
    const int blk  = blockIdx.x;
    const int b    = blk >> 7;        // 128 blocks per batch (LL/WPB)
    const int qg   = blk & 127;

    const float* Yb  = Y  + (size_t)b * MM * 3;
    const int*   Ymb = Ym + (size_t)b * MM;
    const int*   Ytb = Yt + (size_t)b * MM;

    // ---- staging: stable compaction of valid candidates (r16, proven) ----
    const int p0 = tid << 2;
    const float4 f0 = *(const float4*)(Yb + 3 * p0);
    const float4 f1 = *(const float4*)(Yb + 3 * p0 + 4);
    const float4 f2 = *(const float4*)(Yb + 3 * p0 + 8);
    const int4   m4 = *(const int4*)(Ymb + p0);
    const int4   t4 = *(const int4*)(Ytb + p0);
    const int v0 = (m4.x != 0), v1 = (m4.y != 0), v2 = (m4.z != 0), v3 = (m4.w != 0);
    const int cnt0 = v0 + v1 + v2 + v3;

    int inc = cnt0;
#pragma unroll
    for (int off = 1; off < 64; off <<= 1) {
        const int t = __shfl_up(inc, off, 64);
        if (lane >= off) inc += t;
    }
    if (lane == 63) sWinc[wv] = inc;
    __syncthreads();
    if (tid < 16) {
        const int x = sWinc[tid];
        int ix = x;
#pragma unroll
        for (int off = 1; off < 16; off <<= 1) {
            const int t = __shfl_up(ix, off, 16);
            if (tid >= off) ix += t;
        }
        sWbase[tid] = ix - x;
        if (tid == 15) sVtot = ix;
    }
    __syncthreads();

    {
        int bs = sWbase[wv] + inc - cnt0;
        int mb = p0 - bs;
        if (v0) { sX[bs]=f0.x; sY[bs]=f0.y; sZ[bs]=f0.z; sT16[bs]=(u16)t4.x; bs++; }
        else    { if (mb < 64) sMidx[mb] = (u16)(p0 + 0); mb++; }
        if (v1) { sX[bs]=f0.w; sY[bs]=f1.x; sZ[bs]=f1.y; sT16[bs]=(u16)t4.y; bs++; }
        else    { if (mb < 64) sMidx[mb] = (u16)(p0 + 1); mb++; }
        if (v2) { sX[bs]=f1.z; sY[bs]=f1.w; sZ[bs]=f2.x; sT16[bs]=(u16)t4.z; bs++; }
        else    { if (mb < 64) sMidx[mb] = (u16)(p0 + 2); mb++; }
        if (v3) { sX[bs]=f2.y; sY[bs]=f2.z; sZ[bs]=f2.w; sT16[bs]=(u16)t4.w; bs++; }
        else    { if (mb < 64) sMidx[mb] = (u16)(p0 + 3); mb++; }
    }
    const int V  = sVtot;
    const int NJ = (V + 127) >> 7;            // 128-slot blocks (~16)
    for (int c = V + tid; c < (NJ << 7); c += TPB) {
        sX[c] = __builtin_inff(); sY[c] = 0.0f; sZ[c] = 0.0f; sT16[c] = 0;
    }
    __syncthreads();

    const int l = qg * WPB + wv;
    const int q = b * LL + l;

    float* out_y = out;
    float* out_t = out + (size_t)BB * LL * KK * 3;
    float* out_m = out_t + (size_t)BB * LL * KK;
    float* out_d = out_m + (size_t)BB * LL * KK;

    // ---- fast path: masked query (verified r2..r32) ----
    if (maskA[q] == 0.0f) {
        if (lane < KK) {
            const int p = lane;
            const size_t o = (size_t)q * KK + lane;
            out_y[3 * o + 0] = Yb[3 * p + 0];
            out_y[3 * o + 1] = Yb[3 * p + 1];
            out_y[3 * o + 2] = Yb[3 * p + 2];
            out_t[o] = (float)Ytb[p];
            out_m[o] = (float)Ymb[p];
            if (lane == 0) out_d[q] = sqrtf(1000.0f);
        }
        return;
    }

    const float cx = CB[3 * q + 0];
    const float cy = CB[3 * q + 1];
    const float cz = CB[3 * q + 2];

    // ---- fused packed distance + per-lane stable top-4 (asc by (v,slot)) --
    float v1f = 3.0e38f, v2f = 3.0e38f, v3f = 3.0e38f, v4f = 3.0e38f;
    u32 J = 0u;                     // byte-packed ids id=(j<<1)|half
    const u32 SEL1 = 0x06050400u;
    const u32 SEL2 = 0x06050004u;
    const u32 SEL3 = 0x06000504u;
    const u32 SEL4 = 0x00060504u;
    auto ins = [&](float v, u32 id) {
        const bool c1 = v < v1f, c2 = v < v2f, c3 = v < v3f, c4 = v < v4f;
        const u32 sel = c1 ? SEL1 : (c2 ? SEL2 : (c3 ? SEL3 : SEL4));
        const u32 Jp  = __builtin_amdgcn_perm(J, id, sel);
        const float n2 = __builtin_amdgcn_fmed3f(v, v1f, v2f);
        const float n3 = __builtin_amdgcn_fmed3f(v, v2f, v3f);
        const float n4 = __builtin_amdgcn_fmed3f(v, v3f, v4f);
        v1f = fminf(v, v1f);
        v2f = n2; v3f = n3; v4f = n4;
        J = c4 ? Jp : J;
    };

    const f32x2 cxx = {cx, cx}, cyy = {cy, cy}, czz = {cz, cz};
#pragma unroll 4
    for (int j = 0; j < NJ; ++j) {
        const int base = (j << 7) + (lane << 1);
        const f32x2 xp = *(const f32x2*)&sX[base];
        const f32x2 yp = *(const f32x2*)&sY[base];
        const f32x2 zp = *(const f32x2*)&sZ[base];
        const f32x2 dx = cxx - xp;
        const f32x2 dy = cyy - yp;
        const f32x2 dz = czz - zp;
        const f32x2 dsq = (dx * dx + dy * dy) + dz * dz;
        ins(dsq.x, (u32)(j << 1));          // slot 2*lane   (lower p)
        ins(dsq.y, (u32)((j << 1) | 1));    // slot 2*lane+1
    }

    auto slotof = [&](u32 id) -> u32 {
        return ((id >> 1) << 7) | (u32)(lane << 1) | (id & 1u);
    };

    const u32 s1 = slotof( J        & 0xFFu);
    const u32 s2 = slotof((J >>  8) & 0xFFu);
    const u32 s3 = slotof((J >> 16) & 0xFFu);
    const u32 s4 = slotof((J >> 24) & 0xFFu);
    u32 h1 = __float_as_uint(v1f) + 1u;
    u32 h2 = __float_as_uint(v2f) + 1u;
    u32 h3 = __float_as_uint(v3f) + 1u;
    u32 h4 = __float_as_uint(v4f) + 1u;
    u64 lref = ((u64)h4 << 32) | s4;     // refill anchor (updated on refill)

    // ---- flat parallel selection; fire -> resumed ladder (r26, proven) ----
    bool ladder = false;
    int  rstart = 0;
    {
        const u32 T = wave_min_u32(h4);   // wave-uniform; depth-6 DPP ladder
        const bool c1 = (h1 <= T), c2 = (h2 <= T), c3 = (h3 <= T), c4 = (h4 <= T);
        const u64 b1 = __ballot(c1), b2 = __ballot(c2);
        const u64 b3 = __ballot(c3), b4 = __ballot(c4);
        const int n1 = __popcll(b1), n2 = __popcll(b2), n3 = __popcll(b3);
        const int total = n1 + n2 + n3 + __popcll(b4);
        if (total > 64) {
            ladder = true;                // P~0: full ladder, chain unshifted
        } else {
            const u64 below = (1ull << lane) - 1ull;
            u64* sE = sExt[wv];
            sE[lane] = SENT;              // pad [total,64)
            if (lane == 24) sR[wv][24] = SENT;   // incomplete-detector
            int pos = __popcll(b1 & below);
            if (c1) sE[pos] = ((u64)h1 << 32) | s1;
            pos = n1 + __popcll(b2 & below);
            if (c2) sE[pos] = ((u64)h2 << 32) | s2;
            pos = n1 + n2 + __popcll(b3 & below);
            if (c3) sE[pos] = ((u64)h3 << 32) | s3;
            pos = n1 + n2 + n3 + __popcll(b4 & below);
            if (c4) sE[pos] = ((u64)h4 << 32) | s4;
            const u64 mk = sE[lane];
            // rank = #(survivors < mine): paired b128 broadcast reads
            int rank = 0;
            const int tot = (total + 7) & ~7;     // multiple of 8 (even)
#pragma unroll 4
            for (int i = 0; i < tot; i += 2) {
                const u64x2 e2 = *(const u64x2*)&sE[i];
                rank += (e2.x < mk) ? 1 : 0;
                rank += (e2.y < mk) ? 1 : 0;
            }
            if (rank < KK && mk != SENT) sR[wv][rank] = mk;
            const u64 K25 = sR[wv][24];   // broadcast; SENT if survivors<25
            if (__any(lref < K25)) {
                // ranks with value < T strictly are unconditionally correct
                // (hidden keys all have value >= T). Resume after them.
                const int scnt = (h1 < T) + (h2 < T) + (h3 < T) + (h4 < T);
                rstart = __popcll(__ballot(h1 < T)) + __popcll(__ballot(h2 < T))
                       + __popcll(__ballot(h3 < T)) + __popcll(__ballot(h4 < T));
                // shift chain past this lane's consumed (value<T) survivors
#pragma unroll
                for (int k = 0; k < 4; ++k)
                    if (k < scnt) { h1 = h2; h2 = h3; h3 = h4; h4 = SENTH; J >>= 8; }
                ladder = true;            // fire => rstart <= 24 (proven)
            }
        }
    }

    // ---- resumed serial extraction (r19/r26 body, proven), winners -> sR --
    if (ladder) {
#pragma unroll 1
        for (int it = rstart; it < KK; ++it) {
            if (__any(h1 == SENTH)) {
                const bool need = (h1 == SENTH);
                u64 found = SENT;
                const int NI = NJ << 1;
#pragma unroll 4
                for (int id = 0; id < NI; ++id) {
                    const u32 s = slotof((u32)id);
                    const float dx = cx - sX[s];
                    const float dy = cy - sY[s];
                    const float dz = cz - sZ[s];
                    const float v = (dx * dx + dy * dy) + dz * dz;
                    const u64 key = ((u64)(__float_as_uint(v) + 1u) << 32) | s;
                    if (key > lref && key < found) found = key;
                }
                if (need) {
                    const u32 s = (u32)found & 0xFFFFu;
                    h1 = (u32)(found >> 32);
                    J = (J & ~0xFFu) | (((s >> 7) << 1) | (s & 1u));
                    lref = found;
                }
            }
            const u32 bv = wave_min_u32(h1);
            const u64 ball = __ballot(h1 == bv);
            bool win = (h1 == bv);
            if (__popcll(ball) != 1) {        // exact value tie: min slot wins
                const u32 vl = slotof(J & 0xFFu);
                u32 cp = win ? vl : 0xFFFFFFFFu;
#pragma unroll
                for (int off = 32; off; off >>= 1) {
                    const u32 o = __shfl_xor(cp, off, 64);
                    cp = (o < cp) ? o : cp;
                }
                win = win && (vl == cp);
            }
            if (win) {                        // unique keys -> exactly one lane
                sR[wv][it] = ((u64)h1 << 32) | slotof(J & 0xFFu);
                h1 = h2; h2 = h3; h3 = h4; h4 = SENTH;
                J >>= 8;
            }
        }
    }

    // ---- merge valid winners with the constant masked run, then output ----
    // Valid winners served from LDS: coords sX/sY/sZ[slot], Yt from sT16,
    // Ym==1 by construction. Global gathers only for masked-run entries.
    u64 myk = 0;
    if (lane < KK) myk = sR[wv][lane];
    const u32 mvh   = (u32)(myk >> 32);
    const u32 mslot = (u32)myk & 0xFFFFu;
    const bool less = (lane < KK) && (mvh < 0x447A0001u);  // v < 1000.0f
    const int nless = __popcll(__ballot(less));
    if (lane < KK) {
        const size_t o = (size_t)q * KK + lane;
        if (lane < nless) {
            out_y[3 * o + 0] = sX[mslot];
            out_y[3 * o + 1] = sY[mslot];
            out_y[3 * o + 2] = sZ[mslot];
            out_t[o] = (float)sT16[mslot];
            out_m[o] = 1.0f;
            if (lane == 0) out_d[q] = sqrtf(__uint_as_float(mvh - 1u));
        } else {
            const int p = (int)sMidx[lane - nless];
            out_y[3 * o + 0] = Yb[3 * p + 0];
            out_y[3 * o + 1] = Yb[3 * p + 1];
            out_y[3 * o + 2] = Yb[3 * p + 2];
            out_t[o] = (float)Ytb[p];
            out_m[o] = 0.0f;
            if (lane == 0) out_d[q] = sqrtf(1000.0f);   // nless==0 outlier
        }
    }
}

extern "C" void kernel_launch(void* const* d_in, const int* in_sizes, int n_in,
                              void* d_out, int out_size, void* d_ws, size_t ws_size,
                              hipStream_t stream) {
    const float* CB   = (const float*)d_in[0];
    const float* mask = (const float*)d_in[1];
    const float* Y    = (const float*)d_in[2];
    const int*   Yt   = (const int*)d_in[3];
    const int*   Ym   = (const int*)d_in[4];
    float* out = (float*)d_out;

    dim3 grid(BB * LL / WPB);
    dim3 block(TPB);
    hipLaunchKernelGGL(knn_kernel, grid, block, 0, stream, CB, mask, Y, Yt, Ym, out);
}